// Round 1
// baseline (16408.603 us; speedup 1.0000x reference)
//
#include <hip/hip_runtime.h>
#include <hip/hip_bf16.h>
#include <math.h>
#include <stddef.h>

// Problem constants (B=4, S=1024, D=1024, E=8, F=4096, H=16, hd=64)
#define TOKS 4096      // B*S
#define DIM  1024
#define FF   4096
#define NEXP 8
#define NHEAD 16
#define HDIM 64
#define SEQ  1024
#define NBATCH 4

__device__ __forceinline__ float gelu_tanh(float x) {
    const float c0 = 0.7978845608028654f;  // sqrt(2/pi)
    float x3 = x * x * x;
    return 0.5f * x * (1.f + tanhf(c0 * (x + 0.044715f * x3)));
}

// ---------------- RMSNorm: one block per token row (1024 elems) ----------------
__global__ __launch_bounds__(256) void rmsnorm_k(const float* __restrict__ x,
                                                 const float* __restrict__ w,
                                                 float* __restrict__ o) {
    int t = blockIdx.x;
    const float4* xp = reinterpret_cast<const float4*>(x + (size_t)t * DIM);
    float4 xv = xp[threadIdx.x];
    float ss = xv.x * xv.x + xv.y * xv.y + xv.z * xv.z + xv.w * xv.w;
    #pragma unroll
    for (int off = 32; off; off >>= 1) ss += __shfl_xor(ss, off);
    __shared__ float red[4];
    if ((threadIdx.x & 63) == 0) red[threadIdx.x >> 6] = ss;
    __syncthreads();
    float tot = red[0] + red[1] + red[2] + red[3];
    float scale = rsqrtf(tot * (1.0f / (float)DIM) + 1e-5f);
    float4 wv = reinterpret_cast<const float4*>(w)[threadIdx.x];
    float4 ov;
    ov.x = xv.x * scale * wv.x;
    ov.y = xv.y * scale * wv.y;
    ov.z = xv.z * scale * wv.z;
    ov.w = xv.w * scale * wv.w;
    reinterpret_cast<float4*>(o + (size_t)t * DIM)[threadIdx.x] = ov;
}

// ---------------- Tiled fp32 GEMM: C[M,N] = A[M,K] @ B[K,N] ----------------
// MODE 0: C = A@B
// MODE 1: C = R + A@B           (residual add)
// MODE 2: C = gelu(A@B)
// MODE 3: C += rs[row*8] * A@B  (row-scaled accumulate; skip rows with scale 0)
// Requires M%64==0, N%64==0, K%16==0 (true for all our shapes).
template <int MODE>
__global__ __launch_bounds__(256) void gemm_k(const float* __restrict__ A,
                                              const float* __restrict__ B,
                                              float* __restrict__ C,
                                              const float* __restrict__ R,
                                              const float* __restrict__ rs,
                                              int K, int N) {
    __shared__ float As[16][68];
    __shared__ float Bs[16][64];
    int tid = threadIdx.x;
    int tx = tid & 15, ty = tid >> 4;
    size_t row0 = (size_t)blockIdx.y * 64;
    size_t col0 = (size_t)blockIdx.x * 64;
    int ar = tid >> 2, ac = (tid & 3) << 2;    // A tile load: 64 rows x 16 cols
    int br = tid >> 4, bc = (tid & 15) << 2;   // B tile load: 16 rows x 64 cols
    const float* Ap = A + (row0 + (size_t)ar) * K + ac;
    const float* Bp = B + (size_t)br * N + col0 + bc;
    float acc[4][4] = {};
    for (int k0 = 0; k0 < K; k0 += 16) {
        float4 av = *reinterpret_cast<const float4*>(Ap + k0);
        float4 bv = *reinterpret_cast<const float4*>(Bp + (size_t)k0 * N);
        __syncthreads();
        As[ac + 0][ar] = av.x;
        As[ac + 1][ar] = av.y;
        As[ac + 2][ar] = av.z;
        As[ac + 3][ar] = av.w;
        *reinterpret_cast<float4*>(&Bs[br][bc]) = bv;
        __syncthreads();
        #pragma unroll
        for (int kk = 0; kk < 16; ++kk) {
            float a0 = As[kk][(ty << 2) + 0];
            float a1 = As[kk][(ty << 2) + 1];
            float a2 = As[kk][(ty << 2) + 2];
            float a3 = As[kk][(ty << 2) + 3];
            float b0 = Bs[kk][(tx << 2) + 0];
            float b1 = Bs[kk][(tx << 2) + 1];
            float b2 = Bs[kk][(tx << 2) + 2];
            float b3 = Bs[kk][(tx << 2) + 3];
            acc[0][0] += a0 * b0; acc[0][1] += a0 * b1; acc[0][2] += a0 * b2; acc[0][3] += a0 * b3;
            acc[1][0] += a1 * b0; acc[1][1] += a1 * b1; acc[1][2] += a1 * b2; acc[1][3] += a1 * b3;
            acc[2][0] += a2 * b0; acc[2][1] += a2 * b1; acc[2][2] += a2 * b2; acc[2][3] += a2 * b3;
            acc[3][0] += a3 * b0; acc[3][1] += a3 * b1; acc[3][2] += a3 * b2; acc[3][3] += a3 * b3;
        }
    }
    #pragma unroll
    for (int i = 0; i < 4; ++i) {
        size_t r = row0 + (size_t)(ty << 2) + i;
        float* cp = C + r * N + col0 + (tx << 2);
        if (MODE == 0) {
            float4 o = {acc[i][0], acc[i][1], acc[i][2], acc[i][3]};
            *reinterpret_cast<float4*>(cp) = o;
        } else if (MODE == 1) {
            const float4 rv = *reinterpret_cast<const float4*>(R + r * N + col0 + (tx << 2));
            float4 o = {rv.x + acc[i][0], rv.y + acc[i][1], rv.z + acc[i][2], rv.w + acc[i][3]};
            *reinterpret_cast<float4*>(cp) = o;
        } else if (MODE == 2) {
            float4 o = {gelu_tanh(acc[i][0]), gelu_tanh(acc[i][1]),
                        gelu_tanh(acc[i][2]), gelu_tanh(acc[i][3])};
            *reinterpret_cast<float4*>(cp) = o;
        } else {
            float w = rs[r * NEXP];
            if (w != 0.f) {
                float4 cv = *reinterpret_cast<const float4*>(cp);
                cv.x += w * acc[i][0];
                cv.y += w * acc[i][1];
                cv.z += w * acc[i][2];
                cv.w += w * acc[i][3];
                *reinterpret_cast<float4*>(cp) = cv;
            }
        }
    }
}

// ---------------- Attention: one wave per query row ----------------
// grid = B*H*(S/4), block = 256 (4 waves). Non-causal softmax over S=1024 keys.
__global__ __launch_bounds__(256) void attn_k(const float* __restrict__ Q,
                                              const float* __restrict__ K,
                                              const float* __restrict__ V,
                                              float* __restrict__ O) {
    __shared__ float sc[4][SEQ];
    __shared__ float qs[4][HDIM];
    int tid = threadIdx.x, lane = tid & 63, wv = tid >> 6;
    int idx = blockIdx.x;
    int q4 = idx & 255;           // S/4 = 256
    int h = (idx >> 8) & 15;
    int b = idx >> 12;
    int qrow = (q4 << 2) + wv;
    size_t base = ((size_t)b * SEQ) * DIM + (size_t)h * HDIM;
    const float* qp = Q + base + (size_t)qrow * DIM;
    qs[wv][lane] = qp[lane];
    __syncthreads();
    float smax = -1e30f;
    for (int k0 = 0; k0 < SEQ; k0 += 64) {
        const float* kp = K + base + (size_t)(k0 + lane) * DIM;
        float s = 0.f;
        #pragma unroll
        for (int d = 0; d < HDIM; d += 4) {
            float4 kv = *reinterpret_cast<const float4*>(kp + d);
            s += qs[wv][d] * kv.x + qs[wv][d + 1] * kv.y + qs[wv][d + 2] * kv.z + qs[wv][d + 3] * kv.w;
        }
        s *= 0.125f;  // 1/sqrt(64)
        sc[wv][k0 + lane] = s;
        smax = fmaxf(smax, s);
    }
    #pragma unroll
    for (int off = 32; off; off >>= 1) smax = fmaxf(smax, __shfl_xor(smax, off));
    float lsum = 0.f;
    for (int k0 = 0; k0 < SEQ; k0 += 64) {
        float p = __expf(sc[wv][k0 + lane] - smax);
        sc[wv][k0 + lane] = p;
        lsum += p;
    }
    #pragma unroll
    for (int off = 32; off; off >>= 1) lsum += __shfl_xor(lsum, off);
    float inv = 1.f / lsum;
    float acc = 0.f;
    const float* vp = V + base + lane;
    #pragma unroll 8
    for (int k = 0; k < SEQ; ++k) acc += sc[wv][k] * vp[(size_t)k * DIM];
    O[base + (size_t)qrow * DIM + lane] = acc * inv;
}

// ---------------- Router: logits + softmax + top2 + dispatch + loss partials ----------------
// one block (256 thr) per token; acc layout: [0]=sum z^2, [1..8]=sum probs, [9..16]=top2 counts
__global__ __launch_bounds__(256) void router_k(const float* __restrict__ h2,
                                                const float* __restrict__ wr,
                                                float* __restrict__ disp,
                                                float* __restrict__ acc) {
    int t = blockIdx.x, tid = threadIdx.x;
    const float* hp = h2 + (size_t)t * DIM;
    float a[8] = {0, 0, 0, 0, 0, 0, 0, 0};
    for (int d = tid; d < DIM; d += 256) {
        float hv = hp[d];
        const float* wp = wr + (size_t)d * NEXP;
        float4 w0 = *reinterpret_cast<const float4*>(wp);
        float4 w1 = *reinterpret_cast<const float4*>(wp + 4);
        a[0] += hv * w0.x; a[1] += hv * w0.y; a[2] += hv * w0.z; a[3] += hv * w0.w;
        a[4] += hv * w1.x; a[5] += hv * w1.y; a[6] += hv * w1.z; a[7] += hv * w1.w;
    }
    #pragma unroll
    for (int e = 0; e < 8; ++e) {
        #pragma unroll
        for (int off = 32; off; off >>= 1) a[e] += __shfl_xor(a[e], off);
    }
    __shared__ float red[4][8];
    if ((tid & 63) == 0) {
        #pragma unroll
        for (int e = 0; e < 8; ++e) red[tid >> 6][e] = a[e];
    }
    __syncthreads();
    if (tid == 0) {
        float lg[8];
        #pragma unroll
        for (int e = 0; e < 8; ++e) lg[e] = red[0][e] + red[1][e] + red[2][e] + red[3][e];
        float mx = lg[0];
        #pragma unroll
        for (int e = 1; e < 8; ++e) mx = fmaxf(mx, lg[e]);
        float p[8], se = 0.f;
        #pragma unroll
        for (int e = 0; e < 8; ++e) { p[e] = __expf(lg[e] - mx); se += p[e]; }
        float inv = 1.f / se;
        #pragma unroll
        for (int e = 0; e < 8; ++e) p[e] *= inv;
        // top-2, ties -> lowest index (matches lax.top_k)
        int i0 = 0;
        #pragma unroll
        for (int e = 1; e < 8; ++e) if (p[e] > p[i0]) i0 = e;
        int i1 = (i0 == 0) ? 1 : 0;
        #pragma unroll
        for (int e = 0; e < 8; ++e) if (e != i0 && p[e] > p[i1]) i1 = e;
        float w0 = p[i0], w1 = p[i1], s = w0 + w1;
        float* dp = disp + (size_t)t * NEXP;
        #pragma unroll
        for (int e = 0; e < 8; ++e) dp[e] = 0.f;
        dp[i0] = w0 / s;
        dp[i1] = w1 / s;
        float z = mx + __logf(se);  // logsumexp of raw logits
        atomicAdd(&acc[0], z * z);
        #pragma unroll
        for (int e = 0; e < 8; ++e) atomicAdd(&acc[1 + e], p[e]);
        atomicAdd(&acc[9 + i0], 1.f);
        atomicAdd(&acc[9 + i1], 1.f);
    }
}

__global__ void loss_k(const float* __restrict__ acc, float* __restrict__ out) {
    float loss = 0.001f * (acc[0] / (float)TOKS);
    float s = 0.f;
    for (int e = 0; e < 8; ++e)
        s += (acc[1 + e] / (float)TOKS) * (acc[9 + e] / (float)TOKS);
    out[0] = loss + (float)NEXP * s;
}

extern "C" void kernel_launch(void* const* d_in, const int* in_sizes, int n_in,
                              void* d_out, int out_size, void* d_ws, size_t ws_size,
                              hipStream_t stream) {
    const float* x    = (const float*)d_in[0];
    const float* ln1w = (const float*)d_in[1];
    const float* ln2w = (const float*)d_in[2];
    const float* wq   = (const float*)d_in[3];
    const float* wk   = (const float*)d_in[4];
    const float* wv   = (const float*)d_in[5];
    const float* wo   = (const float*)d_in[6];
    const float* wr   = (const float*)d_in[7];
    const float* w1   = (const float*)d_in[8];
    const float* w2   = (const float*)d_in[9];
    float* xo = (float*)d_out;                 // [TOKS*DIM] output, then [1] loss

    // workspace layout (floats)
    float* ws   = (float*)d_ws;
    const size_t NTD = (size_t)TOKS * DIM;     // 4M floats
    float* h    = ws;                          // rms1 out
    float* qb   = h + NTD;
    float* kb   = qb + NTD;
    float* vb   = kb + NTD;
    float* ctx  = vb + NTD;
    float* h2   = ctx + NTD;
    float* he   = h2 + NTD;                    // 1024 x 4096 chunk buffer
    float* disp = he + (size_t)1024 * FF;      // TOKS x 8
    float* lacc = disp + (size_t)TOKS * NEXP;  // 17 floats

    // 1) h = rmsnorm(x, ln1_w)
    rmsnorm_k<<<TOKS, 256, 0, stream>>>(x, ln1w, h);

    // 2) q,k,v = h @ {wq,wk,wv}   [4096,1024]x[1024,1024]
    dim3 gqkv(DIM / 64, TOKS / 64);
    gemm_k<0><<<gqkv, 256, 0, stream>>>(h, wq, qb, nullptr, nullptr, DIM, DIM);
    gemm_k<0><<<gqkv, 256, 0, stream>>>(h, wk, kb, nullptr, nullptr, DIM, DIM);
    gemm_k<0><<<gqkv, 256, 0, stream>>>(h, wv, vb, nullptr, nullptr, DIM, DIM);

    // 3) attention -> ctx
    attn_k<<<NBATCH * NHEAD * (SEQ / 4), 256, 0, stream>>>(qb, kb, vb, ctx);

    // 4) x1 = x + ctx @ wo  -> write into d_out
    gemm_k<1><<<gqkv, 256, 0, stream>>>(ctx, wo, xo, x, nullptr, DIM, DIM);

    // 5) h2 = rmsnorm(x1, ln2_w)
    rmsnorm_k<<<TOKS, 256, 0, stream>>>(xo, ln2w, h2);

    // 6) router (fused logits/softmax/top2/dispatch/loss partials)
    hipMemsetAsync(lacc, 0, 17 * sizeof(float), stream);
    router_k<<<TOKS, 256, 0, stream>>>(h2, wr, disp, lacc);

    // 7) experts (dense: dispatch weight is 0 for non-selected), 1024-row chunks
    for (int e = 0; e < NEXP; ++e) {
        const float* w1e = w1 + (size_t)e * DIM * FF;
        const float* w2e = w2 + (size_t)e * FF * DIM;
        for (int c = 0; c < 4; ++c) {
            const float* a  = h2 + (size_t)c * 1024 * DIM;
            float* outc     = xo + (size_t)c * 1024 * DIM;
            const float* rsc = disp + (size_t)c * 1024 * NEXP + e;
            // he = gelu(a @ w1[e])   [1024,1024]x[1024,4096]
            gemm_k<2><<<dim3(FF / 64, 1024 / 64), 256, 0, stream>>>(a, w1e, he, nullptr, nullptr, DIM, FF);
            // outc += disp[:,e] * (he @ w2[e])   [1024,4096]x[4096,1024]
            gemm_k<3><<<dim3(DIM / 64, 1024 / 64), 256, 0, stream>>>(he, w2e, outc, nullptr, rsc, FF, DIM);
        }
    }

    // 8) finalize router loss
    loss_k<<<1, 1, 0, stream>>>(lacc, xo + NTD);
}

// Round 2
// 2824.132 us; speedup vs baseline: 5.8101x; 5.8101x over previous
//
#include <hip/hip_runtime.h>
#include <hip/hip_bf16.h>
#include <math.h>
#include <stddef.h>
#include <stdint.h>

#define TOKS 4096
#define DIM  1024
#define FF   4096
#define NEXP 8
#define NHEAD 16
#define HDIM 64
#define SEQ  1024
#define NBATCH 4

typedef __attribute__((ext_vector_type(8))) short short8;   // 8 bf16 (4 VGPR)
typedef __attribute__((ext_vector_type(4))) float f32x4;
typedef unsigned short u16;

__device__ __forceinline__ u16 f2bf(float f) {
    __hip_bfloat16 b = __float2bfloat16(f);
    return *reinterpret_cast<u16*>(&b);
}

__device__ __forceinline__ float gelu_tanh(float x) {
    const float c0 = 0.7978845608028654f;  // sqrt(2/pi)
    float x3 = x * x * x;
    return 0.5f * x * (1.f + tanhf(c0 * (x + 0.044715f * x3)));
}

// async global->LDS, 16 bytes per lane (linear LDS dest: base + lane*16)
__device__ __forceinline__ void gl2lds16(const void* g, void* l) {
    __builtin_amdgcn_global_load_lds((const __attribute__((address_space(1))) void*)g,
                                     (__attribute__((address_space(3))) void*)l,
                                     16, 0, 0);
}

// ---------------- RMSNorm: bf16 out (+ optional fp32 out) ----------------
__global__ __launch_bounds__(256) void rmsnorm_k(const float* __restrict__ x,
                                                 const float* __restrict__ w,
                                                 u16* __restrict__ ob,
                                                 float* __restrict__ of) {
    int t = blockIdx.x;
    float4 xv = reinterpret_cast<const float4*>(x + (size_t)t * DIM)[threadIdx.x];
    float ss = xv.x * xv.x + xv.y * xv.y + xv.z * xv.z + xv.w * xv.w;
    #pragma unroll
    for (int off = 32; off; off >>= 1) ss += __shfl_xor(ss, off);
    __shared__ float red[4];
    if ((threadIdx.x & 63) == 0) red[threadIdx.x >> 6] = ss;
    __syncthreads();
    float tot = red[0] + red[1] + red[2] + red[3];
    float scale = rsqrtf(tot * (1.0f / (float)DIM) + 1e-5f);
    float4 wv = reinterpret_cast<const float4*>(w)[threadIdx.x];
    float4 ov;
    ov.x = xv.x * scale * wv.x;
    ov.y = xv.y * scale * wv.y;
    ov.z = xv.z * scale * wv.z;
    ov.w = xv.w * scale * wv.w;
    ushort4 pk;
    pk.x = f2bf(ov.x); pk.y = f2bf(ov.y); pk.z = f2bf(ov.z); pk.w = f2bf(ov.w);
    *reinterpret_cast<ushort4*>(ob + (size_t)t * DIM + threadIdx.x * 4) = pk;
    if (of) *reinterpret_cast<float4*>(of + (size_t)t * DIM + threadIdx.x * 4) = ov;
}

// ---------------- transpose+convert: in[K][N] fp32 -> out[N][K] bf16 ----------------
__global__ __launch_bounds__(256) void tconv_k(const float* __restrict__ in,
                                               u16* __restrict__ out,
                                               int K, int N) {
    __shared__ float tile[64][65];
    int r0 = blockIdx.y * 64, c0 = blockIdx.x * 64;
    int t = threadIdx.x;
    #pragma unroll
    for (int i = 0; i < 4; ++i) {
        int r = (t >> 4) + i * 16;
        float4 v = *reinterpret_cast<const float4*>(&in[(size_t)(r0 + r) * N + c0 + (t & 15) * 4]);
        tile[r][(t & 15) * 4 + 0] = v.x;
        tile[r][(t & 15) * 4 + 1] = v.y;
        tile[r][(t & 15) * 4 + 2] = v.z;
        tile[r][(t & 15) * 4 + 3] = v.w;
    }
    __syncthreads();
    int c = t >> 2, rr = (t & 3) * 16;
    short8 v0, v1;
    #pragma unroll
    for (int u = 0; u < 8; ++u) v0[u] = (short)f2bf(tile[rr + u][c]);
    #pragma unroll
    for (int u = 0; u < 8; ++u) v1[u] = (short)f2bf(tile[rr + 8 + u][c]);
    *reinterpret_cast<short8*>(&out[(size_t)(c0 + c) * K + r0 + rr]) = v0;
    *reinterpret_cast<short8*>(&out[(size_t)(c0 + c) * K + r0 + rr + 8]) = v1;
}

// ---------------- V transpose per head: vb[B*S][D] bf16 -> vt[BH][64][S] bf16 ----------------
__global__ __launch_bounds__(256) void vtrans_k(const u16* __restrict__ vb,
                                                u16* __restrict__ vt) {
    __shared__ u16 tile[64][80];
    int bh = blockIdx.y;
    int b = bh >> 4, h = bh & 15;
    int s0 = blockIdx.x * 64;
    int t = threadIdx.x;
    #pragma unroll
    for (int i = 0; i < 2; ++i) {
        int chunk = i * 256 + t;
        int r = chunk >> 3;           // s row in tile
        int c = (chunk & 7) * 8;      // d col
        short8 v = *reinterpret_cast<const short8*>(
            &vb[(size_t)(b * SEQ + s0 + r) * DIM + h * HDIM + c]);
        *reinterpret_cast<short8*>(&tile[r][c]) = v;
    }
    __syncthreads();
    int d = t >> 2, s16 = (t & 3) * 16;
    short8 o0, o1;
    #pragma unroll
    for (int u = 0; u < 8; ++u) o0[u] = (short)tile[s16 + u][d];
    #pragma unroll
    for (int u = 0; u < 8; ++u) o1[u] = (short)tile[s16 + 8 + u][d];
    size_t ob = ((size_t)bh * HDIM + d) * SEQ + s0 + s16;
    *reinterpret_cast<short8*>(&vt[ob]) = o0;
    *reinterpret_cast<short8*>(&vt[ob + 8]) = o1;
}

// ---------------- MFMA GEMM: C[M,N] = A[M,K] @ B[K,N], Bt = B^T stored [N][K] ----------------
// MODE 0: C(bf16) = A@B
// MODE 1: C(f32)  = R + A@B
// MODE 2: C(bf16) = gelu(A@B)
// MODE 3: C(f32) += rs[row*8] * A@B
// 128x128 tile, BK=64, 4 waves (each 64x64 quadrant), global_load_lds staging.
template <int MODE>
__global__ __launch_bounds__(256) void mgemm(const u16* __restrict__ A,
                                             const u16* __restrict__ Bt,
                                             void* __restrict__ Cv,
                                             const float* __restrict__ R,
                                             const float* __restrict__ rs,
                                             int K, int N) {
    __shared__ __align__(16) u16 As[128 * 64];
    __shared__ __align__(16) u16 Bs[128 * 64];
    const int tid = threadIdx.x;
    const int lane = tid & 63;
    const int w = tid >> 6;
    const int wr = w >> 1, wc = w & 1;
    const int lo = lane & 15, hi = lane >> 4;
    const size_t row0 = (size_t)blockIdx.y * 128;
    const size_t col0 = (size_t)blockIdx.x * 128;
    const u16* Abase = A + row0 * K;
    const u16* Bbase = Bt + col0 * K;

    f32x4 acc[4][4];
    #pragma unroll
    for (int m = 0; m < 4; ++m)
        #pragma unroll
        for (int n = 0; n < 4; ++n) acc[m][n] = (f32x4){0.f, 0.f, 0.f, 0.f};

    for (int k0 = 0; k0 < K; k0 += 64) {
        #pragma unroll
        for (int i = 0; i < 4; ++i) {
            int chunk = i * 256 + tid;
            int r = chunk >> 3;
            int c = (chunk & 7) << 3;
            gl2lds16(Abase + (size_t)r * K + k0 + c, &As[chunk * 8]);
        }
        #pragma unroll
        for (int i = 0; i < 4; ++i) {
            int chunk = i * 256 + tid;
            int r = chunk >> 3;
            int c = (chunk & 7) << 3;
            gl2lds16(Bbase + (size_t)r * K + k0 + c, &Bs[chunk * 8]);
        }
        __syncthreads();
        #pragma unroll
        for (int ks = 0; ks < 2; ++ks) {
            short8 a[4], b[4];
            #pragma unroll
            for (int m = 0; m < 4; ++m)
                a[m] = *reinterpret_cast<const short8*>(
                    &As[(wr * 64 + m * 16 + lo) * 64 + ks * 32 + hi * 8]);
            #pragma unroll
            for (int n = 0; n < 4; ++n)
                b[n] = *reinterpret_cast<const short8*>(
                    &Bs[(wc * 64 + n * 16 + lo) * 64 + ks * 32 + hi * 8]);
            #pragma unroll
            for (int m = 0; m < 4; ++m)
                #pragma unroll
                for (int n = 0; n < 4; ++n)
                    acc[m][n] = __builtin_amdgcn_mfma_f32_16x16x32_bf16(a[m], b[n], acc[m][n], 0, 0, 0);
        }
        __syncthreads();
    }

    #pragma unroll
    for (int m = 0; m < 4; ++m) {
        #pragma unroll
        for (int j = 0; j < 4; ++j) {
            size_t r = row0 + wr * 64 + m * 16 + hi * 4 + j;
            float wt;
            if (MODE == 3) wt = rs[r * NEXP];
            #pragma unroll
            for (int n = 0; n < 4; ++n) {
                size_t cc = col0 + wc * 64 + n * 16 + lo;
                float v = acc[m][n][j];
                if (MODE == 0) {
                    ((u16*)Cv)[r * N + cc] = f2bf(v);
                } else if (MODE == 1) {
                    ((float*)Cv)[r * N + cc] = R[r * N + cc] + v;
                } else if (MODE == 2) {
                    ((u16*)Cv)[r * N + cc] = f2bf(gelu_tanh(v));
                } else {
                    if (wt != 0.f) ((float*)Cv)[r * N + cc] += wt * v;
                }
            }
        }
    }
}

// ---------------- Flash attention (bf16 MFMA, online softmax) ----------------
// grid: (BH * S/64); block 256 (4 waves, 16 q-rows each). KV tiles of 64 keys.
__global__ __launch_bounds__(256) void fattn(const u16* __restrict__ Q,
                                             const u16* __restrict__ Kb,
                                             const u16* __restrict__ Vt,
                                             u16* __restrict__ O) {
    __shared__ __align__(16) char Ks[64 * 128];     // [key][hd] swizzled
    __shared__ __align__(16) char Vs[64 * 128];     // [hd][key] swizzled
    __shared__ __align__(16) char Ps[4][16 * 128];  // per-wave P [q][key] swizzled
    const int tid = threadIdx.x, lane = tid & 63, w = tid >> 6;
    const int lo = lane & 15, hi = lane >> 4;
    const int qt = blockIdx.x & 15;
    const int bh = blockIdx.x >> 4;
    const int b = bh >> 4, h = bh & 15;

    // Q fragments (held in regs across all KV tiles)
    size_t qtok = (size_t)(b * SEQ + qt * 64 + w * 16 + lo);
    short8 qf[2];
    #pragma unroll
    for (int ks = 0; ks < 2; ++ks)
        qf[ks] = *reinterpret_cast<const short8*>(&Q[qtok * DIM + h * HDIM + ks * 32 + hi * 8]);

    float m_r[4], l_r[4];
    f32x4 oa[4];
    #pragma unroll
    for (int j = 0; j < 4; ++j) { m_r[j] = -1e30f; l_r[j] = 0.f; }
    #pragma unroll
    for (int n = 0; n < 4; ++n) oa[n] = (f32x4){0.f, 0.f, 0.f, 0.f};

    const size_t kbase = ((size_t)b * SEQ) * DIM + h * HDIM;
    const size_t vbase = ((size_t)bh * HDIM) * SEQ;
    char* P = Ps[w];

    for (int kt = 0; kt < 16; ++kt) {
        __syncthreads();
        // stage K tile (swizzled): row=key, 128B/row
        #pragma unroll
        for (int i = 0; i < 2; ++i) {
            int chunk = i * 256 + tid;
            int r = chunk >> 3;
            int cb = (chunk & 7) << 4;
            short8 v = *reinterpret_cast<const short8*>(
                &Kb[kbase + (size_t)(kt * 64 + r) * DIM + (cb >> 1)]);
            *reinterpret_cast<short8*>(&Ks[r * 128 + (cb ^ ((r & 7) << 4))]) = v;
        }
        // stage V^T tile (swizzled): row=hd, cols=keys
        #pragma unroll
        for (int i = 0; i < 2; ++i) {
            int chunk = i * 256 + tid;
            int r = chunk >> 3;
            int cb = (chunk & 7) << 4;
            short8 v = *reinterpret_cast<const short8*>(
                &Vt[vbase + (size_t)r * SEQ + kt * 64 + (cb >> 1)]);
            *reinterpret_cast<short8*>(&Vs[r * 128 + (cb ^ ((r & 7) << 4))]) = v;
        }
        __syncthreads();

        // S = (Q K^T) * 0.125
        f32x4 s[4];
        #pragma unroll
        for (int n = 0; n < 4; ++n) {
            f32x4 z = {0.f, 0.f, 0.f, 0.f};
            #pragma unroll
            for (int ks = 0; ks < 2; ++ks) {
                int row = n * 16 + lo;                 // key
                int cb = (ks * 32 + hi * 8) * 2;
                short8 kf = *reinterpret_cast<const short8*>(
                    &Ks[row * 128 + (cb ^ ((row & 7) << 4))]);
                z = __builtin_amdgcn_mfma_f32_16x16x32_bf16(qf[ks], kf, z, 0, 0, 0);
            }
            s[n] = z * 0.125f;
        }

        // online softmax (rows: q = hi*4+j; reduce over n and the 16-lane lo group)
        float mx[4];
        #pragma unroll
        for (int j = 0; j < 4; ++j) {
            mx[j] = fmaxf(fmaxf(s[0][j], s[1][j]), fmaxf(s[2][j], s[3][j]));
            #pragma unroll
            for (int off = 1; off < 16; off <<= 1) mx[j] = fmaxf(mx[j], __shfl_xor(mx[j], off));
        }
        float corr[4], rsum[4];
        #pragma unroll
        for (int j = 0; j < 4; ++j) {
            float mn = fmaxf(m_r[j], mx[j]);
            corr[j] = __expf(m_r[j] - mn);
            m_r[j] = mn;
            rsum[j] = 0.f;
        }
        #pragma unroll
        for (int n = 0; n < 4; ++n)
            #pragma unroll
            for (int j = 0; j < 4; ++j) {
                float p = __expf(s[n][j] - m_r[j]);
                s[n][j] = p;
                rsum[j] += p;
            }
        #pragma unroll
        for (int j = 0; j < 4; ++j) {
            #pragma unroll
            for (int off = 1; off < 16; off <<= 1) rsum[j] += __shfl_xor(rsum[j], off);
            l_r[j] = l_r[j] * corr[j] + rsum[j];
        }
        #pragma unroll
        for (int n = 0; n < 4; ++n)
            #pragma unroll
            for (int j = 0; j < 4; ++j) oa[n][j] *= corr[j];

        // P -> wave-local LDS (bf16, swizzled)
        #pragma unroll
        for (int n = 0; n < 4; ++n)
            #pragma unroll
            for (int j = 0; j < 4; ++j) {
                int q = hi * 4 + j;
                int key = n * 16 + lo;
                *reinterpret_cast<u16*>(&P[q * 128 + ((key * 2) ^ ((q & 7) << 4))]) =
                    f2bf(s[n][j]);
            }

        // O += P @ V
        #pragma unroll
        for (int ks = 0; ks < 2; ++ks) {
            int keyb = (ks * 32 + hi * 8) * 2;
            short8 pf = *reinterpret_cast<const short8*>(
                &P[lo * 128 + (keyb ^ ((lo & 7) << 4))]);
            #pragma unroll
            for (int n = 0; n < 4; ++n) {
                int d = n * 16 + lo;
                short8 vf = *reinterpret_cast<const short8*>(
                    &Vs[d * 128 + (keyb ^ ((d & 7) << 4))]);
                oa[n] = __builtin_amdgcn_mfma_f32_16x16x32_bf16(pf, vf, oa[n], 0, 0, 0);
            }
        }
    }

    #pragma unroll
    for (int j = 0; j < 4; ++j) l_r[j] = 1.f / l_r[j];
    size_t otok = (size_t)(b * SEQ + qt * 64 + w * 16);
    #pragma unroll
    for (int n = 0; n < 4; ++n)
        #pragma unroll
        for (int j = 0; j < 4; ++j)
            O[(otok + hi * 4 + j) * DIM + h * HDIM + n * 16 + lo] = f2bf(oa[n][j] * l_r[j]);
}

// ---------------- Router (fp32): logits+softmax+top2+dispatch+loss partials ----------------
__global__ __launch_bounds__(256) void router_k(const float* __restrict__ h2,
                                                const float* __restrict__ wr,
                                                float* __restrict__ disp,
                                                float* __restrict__ acc) {
    int t = blockIdx.x, tid = threadIdx.x;
    const float* hp = h2 + (size_t)t * DIM;
    float a[8] = {0, 0, 0, 0, 0, 0, 0, 0};
    for (int d = tid; d < DIM; d += 256) {
        float hv = hp[d];
        const float* wp = wr + (size_t)d * NEXP;
        float4 w0 = *reinterpret_cast<const float4*>(wp);
        float4 w1 = *reinterpret_cast<const float4*>(wp + 4);
        a[0] += hv * w0.x; a[1] += hv * w0.y; a[2] += hv * w0.z; a[3] += hv * w0.w;
        a[4] += hv * w1.x; a[5] += hv * w1.y; a[6] += hv * w1.z; a[7] += hv * w1.w;
    }
    #pragma unroll
    for (int e = 0; e < 8; ++e) {
        #pragma unroll
        for (int off = 32; off; off >>= 1) a[e] += __shfl_xor(a[e], off);
    }
    __shared__ float red[4][8];
    if ((tid & 63) == 0) {
        #pragma unroll
        for (int e = 0; e < 8; ++e) red[tid >> 6][e] = a[e];
    }
    __syncthreads();
    if (tid == 0) {
        float lg[8];
        #pragma unroll
        for (int e = 0; e < 8; ++e) lg[e] = red[0][e] + red[1][e] + red[2][e] + red[3][e];
        float mx = lg[0];
        #pragma unroll
        for (int e = 1; e < 8; ++e) mx = fmaxf(mx, lg[e]);
        float p[8], se = 0.f;
        #pragma unroll
        for (int e = 0; e < 8; ++e) { p[e] = __expf(lg[e] - mx); se += p[e]; }
        float inv = 1.f / se;
        #pragma unroll
        for (int e = 0; e < 8; ++e) p[e] *= inv;
        int i0 = 0;
        #pragma unroll
        for (int e = 1; e < 8; ++e) if (p[e] > p[i0]) i0 = e;
        int i1 = (i0 == 0) ? 1 : 0;
        #pragma unroll
        for (int e = 0; e < 8; ++e) if (e != i0 && p[e] > p[i1]) i1 = e;
        float w0 = p[i0], w1 = p[i1], s = w0 + w1;
        float* dp = disp + (size_t)t * NEXP;
        #pragma unroll
        for (int e = 0; e < 8; ++e) dp[e] = 0.f;
        dp[i0] = w0 / s;
        dp[i1] = w1 / s;
        float z = mx + __logf(se);
        atomicAdd(&acc[0], z * z);
        #pragma unroll
        for (int e = 0; e < 8; ++e) atomicAdd(&acc[1 + e], p[e]);
        atomicAdd(&acc[9 + i0], 1.f);
        atomicAdd(&acc[9 + i1], 1.f);
    }
}

__global__ void loss_k(const float* __restrict__ acc, float* __restrict__ out) {
    float loss = 0.001f * (acc[0] / (float)TOKS);
    float s = 0.f;
    for (int e = 0; e < 8; ++e)
        s += (acc[1 + e] / (float)TOKS) * (acc[9 + e] / (float)TOKS);
    out[0] = loss + (float)NEXP * s;
}

extern "C" void kernel_launch(void* const* d_in, const int* in_sizes, int n_in,
                              void* d_out, int out_size, void* d_ws, size_t ws_size,
                              hipStream_t stream) {
    const float* x    = (const float*)d_in[0];
    const float* ln1w = (const float*)d_in[1];
    const float* ln2w = (const float*)d_in[2];
    const float* wq   = (const float*)d_in[3];
    const float* wk   = (const float*)d_in[4];
    const float* wv   = (const float*)d_in[5];
    const float* wo   = (const float*)d_in[6];
    const float* wr   = (const float*)d_in[7];
    const float* w1   = (const float*)d_in[8];
    const float* w2   = (const float*)d_in[9];
    float* xo = (float*)d_out;

    char* p = (char*)d_ws;
    auto alloc = [&](size_t bytes) {
        char* q = p;
        p += (bytes + 255) & ~(size_t)255;
        return q;
    };
    const size_t NTD = (size_t)TOKS * DIM;
    u16* h_bf = (u16*)alloc(NTD * 2);
    u16* wqT  = (u16*)alloc((size_t)DIM * DIM * 2);
    u16* wkT  = (u16*)alloc((size_t)DIM * DIM * 2);
    u16* wvT  = (u16*)alloc((size_t)DIM * DIM * 2);
    u16* woT  = (u16*)alloc((size_t)DIM * DIM * 2);
    u16* qb   = (u16*)alloc(NTD * 2);
    u16* kb   = (u16*)alloc(NTD * 2);
    u16* vt   = (u16*)alloc(NTD * 2);
    u16* ctx  = (u16*)alloc(NTD * 2);
    float* h2f = (float*)alloc(NTD * 4);
    u16* h2b  = (u16*)alloc(NTD * 2);
    u16* w1T  = (u16*)alloc((size_t)DIM * FF * 2);
    u16* w2T  = (u16*)alloc((size_t)FF * DIM * 2);
    u16* he   = (u16*)alloc((size_t)2048 * FF * 2);   // 16 MB chunk buffer
    u16* vb   = he;                                   // alias: vb dead before experts
    float* disp = (float*)alloc((size_t)TOKS * NEXP * 4);
    float* lacc = (float*)alloc(32 * 4);

    // attention-path weight transposes (fp32 -> bf16 [N][K])
    tconv_k<<<dim3(16, 16), 256, 0, stream>>>(wq, wqT, DIM, DIM);
    tconv_k<<<dim3(16, 16), 256, 0, stream>>>(wk, wkT, DIM, DIM);
    tconv_k<<<dim3(16, 16), 256, 0, stream>>>(wv, wvT, DIM, DIM);
    tconv_k<<<dim3(16, 16), 256, 0, stream>>>(wo, woT, DIM, DIM);

    // h = rmsnorm(x)
    rmsnorm_k<<<TOKS, 256, 0, stream>>>(x, ln1w, h_bf, nullptr);

    // q,k,v
    dim3 gqkv(DIM / 128, TOKS / 128);
    mgemm<0><<<gqkv, 256, 0, stream>>>(h_bf, wqT, qb, nullptr, nullptr, DIM, DIM);
    mgemm<0><<<gqkv, 256, 0, stream>>>(h_bf, wkT, kb, nullptr, nullptr, DIM, DIM);
    mgemm<0><<<gqkv, 256, 0, stream>>>(h_bf, wvT, vb, nullptr, nullptr, DIM, DIM);

    // per-head V transpose, then flash attention
    vtrans_k<<<dim3(SEQ / 64, NBATCH * NHEAD), 256, 0, stream>>>(vb, vt);
    fattn<<<NBATCH * NHEAD * (SEQ / 64), 256, 0, stream>>>(qb, kb, vt, ctx);

    // x1 = x + ctx @ wo
    mgemm<1><<<gqkv, 256, 0, stream>>>(ctx, woT, xo, x, nullptr, DIM, DIM);

    // h2 = rmsnorm(x1) (bf16 + fp32)
    rmsnorm_k<<<TOKS, 256, 0, stream>>>(xo, ln2w, h2b, h2f);

    // router
    hipMemsetAsync(lacc, 0, 17 * sizeof(float), stream);
    router_k<<<TOKS, 256, 0, stream>>>(h2f, wr, disp, lacc);

    // experts (dense; weights converted per expert into reused buffers)
    for (int e = 0; e < NEXP; ++e) {
        tconv_k<<<dim3(FF / 64, DIM / 64), 256, 0, stream>>>(w1 + (size_t)e * DIM * FF, w1T, DIM, FF);
        tconv_k<<<dim3(DIM / 64, FF / 64), 256, 0, stream>>>(w2 + (size_t)e * FF * DIM, w2T, FF, DIM);
        for (int c = 0; c < 2; ++c) {
            u16* a = h2b + (size_t)c * 2048 * DIM;
            float* outc = xo + (size_t)c * 2048 * DIM;
            const float* rsc = disp + (size_t)c * 2048 * NEXP + e;
            mgemm<2><<<dim3(FF / 128, 2048 / 128), 256, 0, stream>>>(a, w1T, he, nullptr, nullptr, DIM, FF);
            mgemm<3><<<dim3(DIM / 128, 2048 / 128), 256, 0, stream>>>(he, w2T, outc, nullptr, rsc, FF, DIM);
        }
    }

    loss_k<<<1, 1, 0, stream>>>(lacc, xo + NTD);
}

// Round 3
// 670.043 us; speedup vs baseline: 24.4889x; 4.2149x over previous
//
#include <hip/hip_runtime.h>
#include <hip/hip_bf16.h>
#include <math.h>
#include <stddef.h>
#include <stdint.h>

#define TOKS 4096
#define DIM  1024
#define FF   4096
#define NEXP 8
#define NHEAD 16
#define HDIM 64
#define SEQ  1024
#define NBATCH 4
#define MAXSLOTS 9216   // 8192 + 8*127 rounded to tile multiple
#define MAXTILES 72

typedef __attribute__((ext_vector_type(8))) short short8;   // 8 bf16
typedef __attribute__((ext_vector_type(4))) float f32x4;
typedef unsigned short u16;

__device__ __forceinline__ u16 f2bf(float f) {
    __hip_bfloat16 b = __float2bfloat16(f);
    return *reinterpret_cast<u16*>(&b);
}

__device__ __forceinline__ float gelu_tanh(float x) {
    const float c0 = 0.7978845608028654f;  // sqrt(2/pi)
    float x3 = x * x * x;
    return 0.5f * x * (1.f + tanhf(c0 * (x + 0.044715f * x3)));
}

// async global->LDS, 16 bytes/lane (LDS dest linear: base + lane*16)
__device__ __forceinline__ void gl2lds16(const void* g, void* l) {
    __builtin_amdgcn_global_load_lds((const __attribute__((address_space(1))) void*)g,
                                     (__attribute__((address_space(3))) void*)l,
                                     16, 0, 0);
}

// ---------------- RMSNorm: bf16 out (+ optional fp32 out) ----------------
__global__ __launch_bounds__(256) void rmsnorm_k(const float* __restrict__ x,
                                                 const float* __restrict__ w,
                                                 u16* __restrict__ ob,
                                                 float* __restrict__ of) {
    int t = blockIdx.x;
    float4 xv = reinterpret_cast<const float4*>(x + (size_t)t * DIM)[threadIdx.x];
    float ss = xv.x * xv.x + xv.y * xv.y + xv.z * xv.z + xv.w * xv.w;
    #pragma unroll
    for (int off = 32; off; off >>= 1) ss += __shfl_xor(ss, off);
    __shared__ float red[4];
    if ((threadIdx.x & 63) == 0) red[threadIdx.x >> 6] = ss;
    __syncthreads();
    float tot = red[0] + red[1] + red[2] + red[3];
    float scale = rsqrtf(tot * (1.0f / (float)DIM) + 1e-5f);
    float4 wv = reinterpret_cast<const float4*>(w)[threadIdx.x];
    float4 ov;
    ov.x = xv.x * scale * wv.x;
    ov.y = xv.y * scale * wv.y;
    ov.z = xv.z * scale * wv.z;
    ov.w = xv.w * scale * wv.w;
    ushort4 pk;
    pk.x = f2bf(ov.x); pk.y = f2bf(ov.y); pk.z = f2bf(ov.z); pk.w = f2bf(ov.w);
    *reinterpret_cast<ushort4*>(ob + (size_t)t * DIM + threadIdx.x * 4) = pk;
    if (of) *reinterpret_cast<float4*>(of + (size_t)t * DIM + threadIdx.x * 4) = ov;
}

// ---------------- V transpose per head: vb[B*S][D] bf16 -> vt[BH][64][S] ----------------
__global__ __launch_bounds__(256) void vtrans_k(const u16* __restrict__ vb,
                                                u16* __restrict__ vt) {
    __shared__ u16 tile[64][80];
    int bh = blockIdx.y;
    int b = bh >> 4, h = bh & 15;
    int s0 = blockIdx.x * 64;
    int t = threadIdx.x;
    #pragma unroll
    for (int i = 0; i < 2; ++i) {
        int chunk = i * 256 + t;
        int r = chunk >> 3;
        int c = (chunk & 7) * 8;
        short8 v = *reinterpret_cast<const short8*>(
            &vb[(size_t)(b * SEQ + s0 + r) * DIM + h * HDIM + c]);
        *reinterpret_cast<short8*>(&tile[r][c]) = v;
    }
    __syncthreads();
    int d = t >> 2, s16 = (t & 3) * 16;
    short8 o0, o1;
    #pragma unroll
    for (int u = 0; u < 8; ++u) o0[u] = (short)tile[s16 + u][d];
    #pragma unroll
    for (int u = 0; u < 8; ++u) o1[u] = (short)tile[s16 + 8 + u][d];
    size_t ob = ((size_t)bh * HDIM + d) * SEQ + s0 + s16;
    *reinterpret_cast<short8*>(&vt[ob]) = o0;
    *reinterpret_cast<short8*>(&vt[ob + 8]) = o1;
}

// ---------------- Weight-streaming MFMA GEMM ----------------
// C[M,N] = A[M,K](bf16) @ B[K,N](fp32, streamed+converted in-kernel)
// MODE 0: C(bf16) = A@B                      (QKV)
// MODE 1: C(f32)  = R + A@B                  (wo + residual)
// MODE 2: C(bf16) = gelu(A@B), A rows gathered via slot_tok, B = w1[tile_e]  (MoE up)
// MODE 3: atomicAdd C(f32) += slot_w * A@B, rows scattered to slot_tok, B = w2[tile_e] (MoE down)
// 128x128 tile, BK=64, 4 waves. A via global_load_lds (linear LDS), B via
// reg-staged fp32->bf16 transpose into padded LDS [128][72] (2-way banks only).
template <int MODE>
__global__ __launch_bounds__(256) void wgemm(const u16* __restrict__ A,
                                             const float* __restrict__ B,
                                             void* __restrict__ Cv,
                                             const float* __restrict__ R,
                                             const int* __restrict__ hdr,
                                             const int* __restrict__ slot_tok,
                                             const float* __restrict__ slot_w,
                                             int K, int N) {
    __shared__ __align__(16) u16 As[128 * 64];
    __shared__ __align__(16) u16 Bs[128 * 72];
    const int tid = threadIdx.x;
    const int lane = tid & 63;
    const int w = tid >> 6;
    const int wr = w >> 1, wc = w & 1;
    const int lo = lane & 15, hi = lane >> 4;
    const int by = blockIdx.y;

    if (MODE >= 2) {
        if (by >= hdr[0]) return;   // beyond active tiles
    }
    const float* Bsrc = B;
    if (MODE >= 2) {
        int e = hdr[1 + by];
        Bsrc = B + (size_t)e * K * N;   // w1[e] or w2[e]
    }
    const size_t row0 = (size_t)by * 128;
    const size_t col0 = (size_t)blockIdx.x * 128;

    // hoist per-row token lookups (MODE 2 gather)
    int tokr[4];
    if (MODE == 2) {
        #pragma unroll
        for (int i = 0; i < 4; ++i)
            tokr[i] = slot_tok[row0 + ((i * 256 + tid) >> 3)];
    }
    const u16* Abase = A + row0 * K;

    // B staging thread mapping
    const int n4 = (tid & 31) << 2;   // n offset 0..124
    const int kq = tid >> 5;          // 0..7

    f32x4 acc[4][4];
    #pragma unroll
    for (int m = 0; m < 4; ++m)
        #pragma unroll
        for (int n = 0; n < 4; ++n) acc[m][n] = (f32x4){0.f, 0.f, 0.f, 0.f};

    for (int k0 = 0; k0 < K; k0 += 64) {
        // --- stage A (async, linear LDS) ---
        #pragma unroll
        for (int i = 0; i < 4; ++i) {
            int chunk = i * 256 + tid;
            int r = chunk >> 3;
            int c = (chunk & 7) << 3;
            const u16* src;
            if (MODE == 2)
                src = A + (size_t)tokr[i] * K + k0 + c;
            else
                src = Abase + (size_t)r * K + k0 + c;
            gl2lds16(src, &As[chunk * 8]);
        }
        // --- stage B: fp32 read, convert, transpose into Bs[n][k] (pad 72) ---
        #pragma unroll
        for (int p = 0; p < 2; ++p) {
            int kk = (p * 8 + kq) << 2;   // 0,4,...,60
            const float* bp = Bsrc + (size_t)(k0 + kk) * N + col0 + n4;
            float4 r0 = *reinterpret_cast<const float4*>(bp);
            float4 r1 = *reinterpret_cast<const float4*>(bp + N);
            float4 r2 = *reinterpret_cast<const float4*>(bp + 2 * (size_t)N);
            float4 r3 = *reinterpret_cast<const float4*>(bp + 3 * (size_t)N);
            ushort4 q0 = {f2bf(r0.x), f2bf(r1.x), f2bf(r2.x), f2bf(r3.x)};
            ushort4 q1 = {f2bf(r0.y), f2bf(r1.y), f2bf(r2.y), f2bf(r3.y)};
            ushort4 q2 = {f2bf(r0.z), f2bf(r1.z), f2bf(r2.z), f2bf(r3.z)};
            ushort4 q3 = {f2bf(r0.w), f2bf(r1.w), f2bf(r2.w), f2bf(r3.w)};
            *reinterpret_cast<ushort4*>(&Bs[(n4 + 0) * 72 + kk]) = q0;
            *reinterpret_cast<ushort4*>(&Bs[(n4 + 1) * 72 + kk]) = q1;
            *reinterpret_cast<ushort4*>(&Bs[(n4 + 2) * 72 + kk]) = q2;
            *reinterpret_cast<ushort4*>(&Bs[(n4 + 3) * 72 + kk]) = q3;
        }
        __syncthreads();
        #pragma unroll
        for (int ks = 0; ks < 2; ++ks) {
            short8 a[4], b[4];
            #pragma unroll
            for (int m = 0; m < 4; ++m)
                a[m] = *reinterpret_cast<const short8*>(
                    &As[(wr * 64 + m * 16 + lo) * 64 + ks * 32 + hi * 8]);
            #pragma unroll
            for (int n = 0; n < 4; ++n)
                b[n] = *reinterpret_cast<const short8*>(
                    &Bs[(wc * 64 + n * 16 + lo) * 72 + ks * 32 + hi * 8]);
            #pragma unroll
            for (int m = 0; m < 4; ++m)
                #pragma unroll
                for (int n = 0; n < 4; ++n)
                    acc[m][n] = __builtin_amdgcn_mfma_f32_16x16x32_bf16(a[m], b[n], acc[m][n], 0, 0, 0);
        }
        __syncthreads();
    }

    #pragma unroll
    for (int m = 0; m < 4; ++m) {
        #pragma unroll
        for (int j = 0; j < 4; ++j) {
            size_t r = row0 + wr * 64 + m * 16 + hi * 4 + j;
            float sw = 0.f;
            int tok = 0;
            if (MODE == 3) {
                sw = slot_w[r];
                tok = slot_tok[r];
                if (sw == 0.f) continue;
            }
            #pragma unroll
            for (int n = 0; n < 4; ++n) {
                size_t cc = col0 + wc * 64 + n * 16 + lo;
                float v = acc[m][n][j];
                if (MODE == 0) {
                    ((u16*)Cv)[r * N + cc] = f2bf(v);
                } else if (MODE == 1) {
                    ((float*)Cv)[r * N + cc] = R[r * N + cc] + v;
                } else if (MODE == 2) {
                    ((u16*)Cv)[r * N + cc] = f2bf(gelu_tanh(v));
                } else {
                    atomicAdd(&((float*)Cv)[(size_t)tok * N + cc], sw * v);
                }
            }
        }
    }
}

// ---------------- Flash attention (bf16 MFMA, online softmax) ----------------
__global__ __launch_bounds__(256) void fattn(const u16* __restrict__ Q,
                                             const u16* __restrict__ Kb,
                                             const u16* __restrict__ Vt,
                                             u16* __restrict__ O) {
    __shared__ __align__(16) char Ks[64 * 128];
    __shared__ __align__(16) char Vs[64 * 128];
    __shared__ __align__(16) char Ps[4][16 * 128];
    const int tid = threadIdx.x, lane = tid & 63, w = tid >> 6;
    const int lo = lane & 15, hi = lane >> 4;
    const int qt = blockIdx.x & 15;
    const int bh = blockIdx.x >> 4;
    const int b = bh >> 4, h = bh & 15;

    size_t qtok = (size_t)(b * SEQ + qt * 64 + w * 16 + lo);
    short8 qf[2];
    #pragma unroll
    for (int ks = 0; ks < 2; ++ks)
        qf[ks] = *reinterpret_cast<const short8*>(&Q[qtok * DIM + h * HDIM + ks * 32 + hi * 8]);

    float m_r[4], l_r[4];
    f32x4 oa[4];
    #pragma unroll
    for (int j = 0; j < 4; ++j) { m_r[j] = -1e30f; l_r[j] = 0.f; }
    #pragma unroll
    for (int n = 0; n < 4; ++n) oa[n] = (f32x4){0.f, 0.f, 0.f, 0.f};

    const size_t kbase = ((size_t)b * SEQ) * DIM + h * HDIM;
    const size_t vbase = ((size_t)bh * HDIM) * SEQ;
    char* P = Ps[w];

    for (int kt = 0; kt < 16; ++kt) {
        __syncthreads();
        #pragma unroll
        for (int i = 0; i < 2; ++i) {
            int chunk = i * 256 + tid;
            int r = chunk >> 3;
            int cb = (chunk & 7) << 4;
            short8 v = *reinterpret_cast<const short8*>(
                &Kb[kbase + (size_t)(kt * 64 + r) * DIM + (cb >> 1)]);
            *reinterpret_cast<short8*>(&Ks[r * 128 + (cb ^ ((r & 7) << 4))]) = v;
        }
        #pragma unroll
        for (int i = 0; i < 2; ++i) {
            int chunk = i * 256 + tid;
            int r = chunk >> 3;
            int cb = (chunk & 7) << 4;
            short8 v = *reinterpret_cast<const short8*>(
                &Vt[vbase + (size_t)r * SEQ + kt * 64 + (cb >> 1)]);
            *reinterpret_cast<short8*>(&Vs[r * 128 + (cb ^ ((r & 7) << 4))]) = v;
        }
        __syncthreads();

        f32x4 s[4];
        #pragma unroll
        for (int n = 0; n < 4; ++n) {
            f32x4 z = {0.f, 0.f, 0.f, 0.f};
            #pragma unroll
            for (int ks = 0; ks < 2; ++ks) {
                int row = n * 16 + lo;
                int cb = (ks * 32 + hi * 8) * 2;
                short8 kf = *reinterpret_cast<const short8*>(
                    &Ks[row * 128 + (cb ^ ((row & 7) << 4))]);
                z = __builtin_amdgcn_mfma_f32_16x16x32_bf16(qf[ks], kf, z, 0, 0, 0);
            }
            s[n] = z * 0.125f;
        }

        float mx[4];
        #pragma unroll
        for (int j = 0; j < 4; ++j) {
            mx[j] = fmaxf(fmaxf(s[0][j], s[1][j]), fmaxf(s[2][j], s[3][j]));
            #pragma unroll
            for (int off = 1; off < 16; off <<= 1) mx[j] = fmaxf(mx[j], __shfl_xor(mx[j], off));
        }
        float corr[4], rsum[4];
        #pragma unroll
        for (int j = 0; j < 4; ++j) {
            float mn = fmaxf(m_r[j], mx[j]);
            corr[j] = __expf(m_r[j] - mn);
            m_r[j] = mn;
            rsum[j] = 0.f;
        }
        #pragma unroll
        for (int n = 0; n < 4; ++n)
            #pragma unroll
            for (int j = 0; j < 4; ++j) {
                float p = __expf(s[n][j] - m_r[j]);
                s[n][j] = p;
                rsum[j] += p;
            }
        #pragma unroll
        for (int j = 0; j < 4; ++j) {
            #pragma unroll
            for (int off = 1; off < 16; off <<= 1) rsum[j] += __shfl_xor(rsum[j], off);
            l_r[j] = l_r[j] * corr[j] + rsum[j];
        }
        #pragma unroll
        for (int n = 0; n < 4; ++n)
            #pragma unroll
            for (int j = 0; j < 4; ++j) oa[n][j] *= corr[j];

        #pragma unroll
        for (int n = 0; n < 4; ++n)
            #pragma unroll
            for (int j = 0; j < 4; ++j) {
                int q = hi * 4 + j;
                int key = n * 16 + lo;
                *reinterpret_cast<u16*>(&P[q * 128 + ((key * 2) ^ ((q & 7) << 4))]) =
                    f2bf(s[n][j]);
            }

        #pragma unroll
        for (int ks = 0; ks < 2; ++ks) {
            int keyb = (ks * 32 + hi * 8) * 2;
            short8 pf = *reinterpret_cast<const short8*>(
                &P[lo * 128 + (keyb ^ ((lo & 7) << 4))]);
            #pragma unroll
            for (int n = 0; n < 4; ++n) {
                int d = n * 16 + lo;
                short8 vf = *reinterpret_cast<const short8*>(
                    &Vs[d * 128 + (keyb ^ ((d & 7) << 4))]);
                oa[n] = __builtin_amdgcn_mfma_f32_16x16x32_bf16(pf, vf, oa[n], 0, 0, 0);
            }
        }
    }

    #pragma unroll
    for (int j = 0; j < 4; ++j) l_r[j] = 1.f / l_r[j];
    size_t otok = (size_t)(b * SEQ + qt * 64 + w * 16);
    #pragma unroll
    for (int n = 0; n < 4; ++n)
        #pragma unroll
        for (int j = 0; j < 4; ++j)
            O[(otok + hi * 4 + j) * DIM + h * HDIM + n * 16 + lo] = f2bf(oa[n][j] * l_r[j]);
}

// ---------------- Router: one wave per token ----------------
// out: esel[t] = e0 | e1<<8, wsel[t] = {w0n, w1n}; lacc partials via block-level atomics
__global__ __launch_bounds__(256) void router_k(const float* __restrict__ h2,
                                                const float* __restrict__ wr,
                                                int* __restrict__ esel,
                                                float2* __restrict__ wsel,
                                                float* __restrict__ lacc) {
    __shared__ float part[17];
    int tid = threadIdx.x, lane = tid & 63, w = tid >> 6;
    if (tid < 17) part[tid] = 0.f;
    __syncthreads();
    int t = blockIdx.x * 4 + w;
    float a[8] = {0, 0, 0, 0, 0, 0, 0, 0};
    #pragma unroll
    for (int j = 0; j < 4; ++j) {
        int d0 = j * 256 + lane * 4;
        float4 hv = *reinterpret_cast<const float4*>(&h2[(size_t)t * DIM + d0]);
        #pragma unroll
        for (int i = 0; i < 4; ++i) {
            float h = (i == 0) ? hv.x : (i == 1) ? hv.y : (i == 2) ? hv.z : hv.w;
            const float* wp = wr + (size_t)(d0 + i) * NEXP;
            float4 w0 = *reinterpret_cast<const float4*>(wp);
            float4 w1 = *reinterpret_cast<const float4*>(wp + 4);
            a[0] += h * w0.x; a[1] += h * w0.y; a[2] += h * w0.z; a[3] += h * w0.w;
            a[4] += h * w1.x; a[5] += h * w1.y; a[6] += h * w1.z; a[7] += h * w1.w;
        }
    }
    #pragma unroll
    for (int e = 0; e < 8; ++e) {
        #pragma unroll
        for (int off = 32; off; off >>= 1) a[e] += __shfl_xor(a[e], off);
    }
    if (lane == 0) {
        float mx = a[0];
        #pragma unroll
        for (int e = 1; e < 8; ++e) mx = fmaxf(mx, a[e]);
        float p[8], se = 0.f;
        #pragma unroll
        for (int e = 0; e < 8; ++e) { p[e] = __expf(a[e] - mx); se += p[e]; }
        float inv = 1.f / se;
        #pragma unroll
        for (int e = 0; e < 8; ++e) p[e] *= inv;
        int i0 = 0;
        #pragma unroll
        for (int e = 1; e < 8; ++e) if (p[e] > p[i0]) i0 = e;
        int i1 = (i0 == 0) ? 1 : 0;
        #pragma unroll
        for (int e = 0; e < 8; ++e) if (e != i0 && p[e] > p[i1]) i1 = e;
        float w0 = p[i0], w1 = p[i1], s = w0 + w1;
        esel[t] = i0 | (i1 << 8);
        wsel[t] = make_float2(w0 / s, w1 / s);
        float z = mx + __logf(se);
        atomicAdd(&part[0], z * z);
        #pragma unroll
        for (int e = 0; e < 8; ++e) atomicAdd(&part[1 + e], p[e]);
        atomicAdd(&part[9 + i0], 1.f);
        atomicAdd(&part[9 + i1], 1.f);
    }
    __syncthreads();
    if (tid < 17) atomicAdd(&lacc[tid], part[tid]);
}

// ---------------- Scheduler: build slot-sorted, 128-padded expert lists ----------------
__global__ __launch_bounds__(256) void sched_k(const int* __restrict__ esel,
                                               const float2* __restrict__ wsel,
                                               int* __restrict__ hdr,
                                               int* __restrict__ slot_tok,
                                               float* __restrict__ slot_w) {
    __shared__ int cnt[8], base[8], cur[8], tot_s;
    int tid = threadIdx.x;
    if (tid < 8) { cnt[tid] = 0; cur[tid] = 0; }
    __syncthreads();
    for (int t = tid; t < TOKS; t += 256) {
        int es = esel[t];
        atomicAdd(&cnt[es & 255], 1);
        atomicAdd(&cnt[(es >> 8) & 255], 1);
    }
    __syncthreads();
    if (tid == 0) {
        int run = 0;
        for (int e = 0; e < 8; ++e) {
            base[e] = run;
            run += (cnt[e] + 127) & ~127;
        }
        tot_s = run;
        hdr[0] = run >> 7;   // ntiles
    }
    __syncthreads();
    int ntiles = tot_s >> 7;
    // tile -> expert map
    for (int T = tid; T < ntiles; T += 256) {
        int r = T << 7;
        int e = 0;
        for (int k = 1; k < 8; ++k) if (r >= base[k]) e = k;
        hdr[1 + T] = e;
    }
    // place tokens
    for (int t = tid; t < TOKS; t += 256) {
        int es = esel[t];
        float2 ww = wsel[t];
        int e0 = es & 255, e1 = (es >> 8) & 255;
        int s0 = base[e0] + atomicAdd(&cur[e0], 1);
        slot_tok[s0] = t; slot_w[s0] = ww.x;
        int s1 = base[e1] + atomicAdd(&cur[e1], 1);
        slot_tok[s1] = t; slot_w[s1] = ww.y;
    }
    __syncthreads();
    // pads: tok 0, weight 0
    for (int idx = tid; idx < 8 * 128; idx += 256) {
        int e = idx >> 7, p2 = idx & 127;
        int c = cnt[e];
        int al = (c + 127) & ~127;
        if (c + p2 < al) {
            int s = base[e] + c + p2;
            slot_tok[s] = 0;
            slot_w[s] = 0.f;
        }
    }
}

__global__ void loss_k(const float* __restrict__ acc, float* __restrict__ out) {
    float loss = 0.001f * (acc[0] / (float)TOKS);
    float s = 0.f;
    for (int e = 0; e < 8; ++e)
        s += (acc[1 + e] / (float)TOKS) * (acc[9 + e] / (float)TOKS);
    out[0] = loss + (float)NEXP * s;
}

extern "C" void kernel_launch(void* const* d_in, const int* in_sizes, int n_in,
                              void* d_out, int out_size, void* d_ws, size_t ws_size,
                              hipStream_t stream) {
    const float* x    = (const float*)d_in[0];
    const float* ln1w = (const float*)d_in[1];
    const float* ln2w = (const float*)d_in[2];
    const float* wq   = (const float*)d_in[3];
    const float* wk   = (const float*)d_in[4];
    const float* wv   = (const float*)d_in[5];
    const float* wo   = (const float*)d_in[6];
    const float* wr   = (const float*)d_in[7];
    const float* w1   = (const float*)d_in[8];
    const float* w2   = (const float*)d_in[9];
    float* xo = (float*)d_out;

    const size_t NTD = (size_t)TOKS * DIM;
    char* p = (char*)d_ws;

    // persistent region (survives into expert phase)
    u16* h2b = (u16*)p;                                    // 8 MB
    int* hdr = (int*)(p + NTD * 2);                        // 128 ints
    int* slot_tok = hdr + 128;                             // 9216 ints
    float* slot_w = (float*)(slot_tok + MAXSLOTS);         // 9216 f
    int* esel = (int*)(slot_w + MAXSLOTS);                 // 4096 ints
    float2* wsel = (float2*)(esel + TOKS);                 // 4096 f2
    float* lacc = (float*)(wsel + TOKS);                   // 32 f

    // transient region (attention-phase buffers; later reused as `he`)
    char* tr = p + 9 * 1024 * 1024;
    u16* he  = (u16*)tr;                                   // 9216 x 4096 bf16 = 72 MB
    u16* h_bf = (u16*)tr;                                  // aliases below
    u16* qb  = h_bf + NTD;
    u16* kb  = qb + NTD;
    u16* vb  = kb + NTD;
    u16* vt  = vb + NTD;
    u16* ctx = vt + NTD;
    float* h2f = (float*)(tr + 48 * 1024 * 1024);          // 16 MB

    // 1) h = rmsnorm(x)
    rmsnorm_k<<<TOKS, 256, 0, stream>>>(x, ln1w, h_bf, nullptr);

    // 2) q,k,v = h @ {wq,wk,wv}  (weights streamed fp32)
    dim3 gqkv(DIM / 128, TOKS / 128);
    wgemm<0><<<gqkv, 256, 0, stream>>>(h_bf, wq, qb, nullptr, nullptr, nullptr, nullptr, DIM, DIM);
    wgemm<0><<<gqkv, 256, 0, stream>>>(h_bf, wk, kb, nullptr, nullptr, nullptr, nullptr, DIM, DIM);
    wgemm<0><<<gqkv, 256, 0, stream>>>(h_bf, wv, vb, nullptr, nullptr, nullptr, nullptr, DIM, DIM);

    // 3) V transpose + flash attention
    vtrans_k<<<dim3(SEQ / 64, NBATCH * NHEAD), 256, 0, stream>>>(vb, vt);
    fattn<<<NBATCH * NHEAD * (SEQ / 64), 256, 0, stream>>>(qb, kb, vt, ctx);

    // 4) x1 = x + ctx @ wo
    wgemm<1><<<gqkv, 256, 0, stream>>>(ctx, wo, xo, x, nullptr, nullptr, nullptr, DIM, DIM);

    // 5) h2 = rmsnorm(x1) -> bf16 + fp32
    rmsnorm_k<<<TOKS, 256, 0, stream>>>(xo, ln2w, h2b, h2f);

    // 6) router + scheduler
    hipMemsetAsync(lacc, 0, 17 * sizeof(float), stream);
    router_k<<<TOKS / 4, 256, 0, stream>>>(h2f, wr, esel, wsel, lacc);
    sched_k<<<1, 256, 0, stream>>>(esel, wsel, hdr, slot_tok, slot_w);

    // 7) MoE up: he[slot] = gelu(h2b[tok] @ w1[e])  — all experts, one dispatch
    wgemm<2><<<dim3(FF / 128, MAXTILES), 256, 0, stream>>>(
        h2b, w1, he, nullptr, hdr, slot_tok, slot_w, DIM, FF);

    // 8) MoE down: xo[tok] += w * (he[slot] @ w2[e]) — all experts, one dispatch
    wgemm<3><<<dim3(DIM / 128, MAXTILES), 256, 0, stream>>>(
        he, w2, xo, nullptr, hdr, slot_tok, slot_w, FF, DIM);

    // 9) router loss
    loss_k<<<1, 1, 0, stream>>>(lacc, xo + NTD);
}